// Round 12
// baseline (220.480 us; speedup 1.0000x reference)
//
#include <hip/hip_runtime.h>
#include <math.h>

#define SEQ   2048
#define HDIM  1024
#define NH    16
#define DH    64
#define MTOT  4096   // B*S
#define BHTOT 32     // B*NH

typedef _Float16 half_t;
typedef __attribute__((ext_vector_type(2))) __fp16 fp16x2;
typedef __attribute__((ext_vector_type(4))) _Float16 half4;
typedef __attribute__((ext_vector_type(8))) _Float16 half8;
typedef __attribute__((ext_vector_type(4))) float float4v;

// async global->LDS DMA, 16 B per lane; LDS dest = wave-uniform base + lane*16
typedef __attribute__((address_space(1))) const unsigned int guint;
typedef __attribute__((address_space(3))) unsigned int luint;
__device__ __forceinline__ void glds16(const half_t* g, half_t* l) {
    __builtin_amdgcn_global_load_lds((guint*)g, (luint*)l, 16, 0, 0);
}

// ---------------- fused prologue: 5 fp32->fp16 casts + rope table ----------------
// 8 floats/thread (two float4 loads -> one uint4 store). Grid 4352.
__global__ __launch_bounds__(256)
void prep(const float* __restrict__ x,  const float* __restrict__ wq,
          const float* __restrict__ wk, const float* __restrict__ wv,
          const float* __restrict__ wo,
          half_t* __restrict__ xh,  half_t* __restrict__ wqh,
          half_t* __restrict__ wkh, half_t* __restrict__ wvh,
          half_t* __restrict__ woh, float2* __restrict__ rope)
{
    const int bid = blockIdx.x;
    if (bid < 4096) {
        int i = bid * 256 + threadIdx.x;   // 0..1048575, 8 floats each
        const float4* s; uint4* d; int j;
        if (i < 524288) { s = (const float4*)x; d = (uint4*)xh; j = i; }
        else {
            int k = i - 524288;
            int w = k >> 17; j = k & 131071;
            s = (const float4*)((w == 0) ? wq : (w == 1) ? wk : (w == 2) ? wv : wo);
            d = (uint4*)((w == 0) ? wqh : (w == 1) ? wkh : (w == 2) ? wvh : woh);
        }
        float4 v0 = s[2 * j], v1 = s[2 * j + 1];
        union { half_t h[8]; uint4 u; } tmp;
        tmp.h[0] = (half_t)v0.x; tmp.h[1] = (half_t)v0.y;
        tmp.h[2] = (half_t)v0.z; tmp.h[3] = (half_t)v0.w;
        tmp.h[4] = (half_t)v1.x; tmp.h[5] = (half_t)v1.y;
        tmp.h[6] = (half_t)v1.z; tmp.h[7] = (half_t)v1.w;
        d[j] = tmp.u;
    } else {
        int tt = (bid - 4096) * 256 + threadIdx.x;   // 0 .. SEQ*32-1
        int s = tt >> 5, j = tt & 31;
        float inv = powf(10000.0f, -(float)j / 32.0f);
        float ang = (float)s * inv;
        rope[tt] = make_float2(cosf(ang), sinf(ang));
    }
}

// ---------------- GEMM: QKV only. C = A(4096x1024,f16) * W^T, 128x128 tiles ----
// BK=32 + double-buffer 2-phase (verified r9: stage(t+1) before compute(t),
// one vmcnt(0)+barrier per iter). 32 KB LDS, line-local swizzle.
__global__ __launch_bounds__(256, 5)
void gemm_qkv(const half_t* __restrict__ A,
              const half_t* __restrict__ w0, const half_t* __restrict__ w1,
              const half_t* __restrict__ w2,
              half_t* __restrict__ Qb, half_t* __restrict__ Kb,
              half_t* __restrict__ Vtb,
              const float2* __restrict__ rope)
{
    const int mode = blockIdx.z;
    const half_t* Bw = (mode == 1) ? w1 : (mode == 2) ? w2 : w0;

    __shared__ __align__(16) half_t Tsh[2][2][128][32];   // [buf][A|B][row][32], 32 KB

    const int t    = threadIdx.x;
    const int lane = t & 63;
    const int wave = t >> 6;
    const int quad = lane >> 4;
    const int l16  = lane & 15;
    const int wr   = (wave >> 1) * 64;
    const int wc   = (wave & 1) * 64;
    const int bm   = blockIdx.x, bn = blockIdx.y;

    // staging: one glds16 covers 16 rows x 64 B; chunk XOR-swizzled by row&3
    const int srow   = lane >> 2;               // 0..15 within a 16-row DMA chunk
    const int schunk = (lane & 3) ^ (srow & 3); // line-local pre-swizzle (16B chunks)
    const half_t* Asrc = A  + (size_t)(bm * 128 + srow) * HDIM + schunk * 8;
    const half_t* Bsrc = Bw + (size_t)(bn * 128 + srow) * HDIM + schunk * 8;
    const int swz = (l16 & 3) << 4;             // read-side XOR (byte offset)

    auto stage = [&](int kt, int buf) {
        const half_t* Ak = Asrc + kt * 32;
        const half_t* Bk = Bsrc + kt * 32;
        glds16(Ak + (size_t)(wave * 32)      * HDIM, &Tsh[buf][0][wave * 32][0]);
        glds16(Ak + (size_t)(wave * 32 + 16) * HDIM, &Tsh[buf][0][wave * 32 + 16][0]);
        glds16(Bk + (size_t)(wave * 32)      * HDIM, &Tsh[buf][1][wave * 32][0]);
        glds16(Bk + (size_t)(wave * 32 + 16) * HDIM, &Tsh[buf][1][wave * 32 + 16][0]);
    };

    float4v acc[4][4] = {};

    stage(0, 0);
    __asm__ volatile("s_waitcnt vmcnt(0)" ::: "memory");
    __builtin_amdgcn_s_barrier();
    __builtin_amdgcn_sched_barrier(0);

    for (int kt = 0; kt < HDIM / 32; ++kt) {
        const int cur = kt & 1, nxt = cur ^ 1;
        if (kt + 1 < HDIM / 32) stage(kt + 1, nxt);   // prefetch under compute
        const int cb = (quad << 4) ^ swz;
        half8 af[4], bf[4];
#pragma unroll
        for (int mb = 0; mb < 4; ++mb)
            af[mb] = *(const half8*)((const char*)&Tsh[cur][0][wr + mb * 16 + l16][0] + cb);
#pragma unroll
        for (int nb = 0; nb < 4; ++nb)
            bf[nb] = *(const half8*)((const char*)&Tsh[cur][1][wc + nb * 16 + l16][0] + cb);
#pragma unroll
        for (int mb = 0; mb < 4; ++mb)
#pragma unroll
            for (int nb = 0; nb < 4; ++nb)
                acc[mb][nb] = __builtin_amdgcn_mfma_f32_16x16x32_f16(af[mb], bf[nb], acc[mb][nb], 0, 0, 0);
        __asm__ volatile("s_waitcnt vmcnt(0)" ::: "memory");  // next tile landed
        __builtin_amdgcn_s_barrier();
        __builtin_amdgcn_sched_barrier(0);
    }

    if (mode == 2) {  // V, transposed store: Vtb[bh][d][s]
#pragma unroll
        for (int mb = 0; mb < 4; ++mb)
#pragma unroll
            for (int nb = 0; nb < 4; ++nb) {
                int row0 = bm * 128 + wr + mb * 16 + quad * 4;
                int col  = bn * 128 + wc + nb * 16 + l16;
                int b = row0 >> 11, s0 = row0 & 2047;
                int h = col >> 6,  dd = col & 63;
                union { half_t h4[4]; uint2 u; } tmp;
#pragma unroll
                for (int r = 0; r < 4; ++r) tmp.h4[r] = (half_t)acc[mb][nb][r];
                *(uint2*)&Vtb[((size_t)((b * NH + h) * DH + dd)) * SEQ + s0] = tmp.u;
            }
        return;
    }
    // mode 0 (Q: rope + scale) / mode 1 (K: rope)
    {
        half_t* Ob = (mode == 0) ? Qb : Kb;
        const float scl = (mode == 0) ? 0.125f * 1.44269504088896f : 1.0f;
        const int h = (bn * 128 + wc) >> 6;   // wave's 64 cols = one head
        // per-wave fp32 bounce [16][68], overlaid on the 32 KB tile LDS
        float* E = (float*)&Tsh[0][0][0][0] + wave * 1088;
#pragma unroll
        for (int mb = 0; mb < 4; ++mb) {
#pragma unroll
            for (int nb = 0; nb < 4; ++nb)
#pragma unroll
                for (int r = 0; r < 4; ++r)
                    E[(quad * 4 + r) * 68 + nb * 16 + l16] = acc[mb][nb][r];
            __asm__ volatile("s_waitcnt lgkmcnt(0)" ::: "memory");  // wave-private region
#pragma unroll
            for (int c = 0; c < 2; ++c) {
                const int uidx = c * 64 + lane;
                const int row = uidx >> 3, ch = uidx & 7;
                const int sg = bm * 128 + wr + mb * 16 + row;
                const int b = sg >> 11, s = sg & 2047;
                const float* Er = E + row * 68 + ch * 8;
                const float4 e0 = *(const float4*)Er;
                const float4 e1 = *(const float4*)(Er + 4);
                const float4* rp = (const float4*)(rope + (size_t)s * 32 + ch * 4);
                const float4 r01 = rp[0];   // cos0,sin0,cos1,sin1
                const float4 r23 = rp[1];
                union { half_t hh[8]; uint4 u; } o;
                o.hh[0] = (half_t)((e0.x * r01.x - e0.y * r01.y) * scl);
                o.hh[1] = (half_t)((e0.x * r01.y + e0.y * r01.x) * scl);
                o.hh[2] = (half_t)((e0.z * r01.z - e0.w * r01.w) * scl);
                o.hh[3] = (half_t)((e0.z * r01.w + e0.w * r01.z) * scl);
                o.hh[4] = (half_t)((e1.x * r23.x - e1.y * r23.y) * scl);
                o.hh[5] = (half_t)((e1.x * r23.y + e1.y * r23.x) * scl);
                o.hh[6] = (half_t)((e1.z * r23.z - e1.w * r23.w) * scl);
                o.hh[7] = (half_t)((e1.z * r23.w + e1.w * r23.z) * scl);
                *(uint4*)&Ob[((size_t)((b * NH + h) * SEQ + s)) * DH + ch * 8] = o.u;
            }
            // per-wave DS ops are in-order: reads above complete before next mb's writes
        }
    }
}

// ---------------- output GEMM: out(f32) = ah(4096x1024,f16) @ wo^T ----------------
// v5: NO LDS, NO BARRIERS. Both operands are row-major over K, so each MFMA
// fragment is a direct 16 B/lane global load: A[row=...+l16][k=kt*32+quad*8],
// W[col=...+l16][k=...]. The 4 quads of each row tile a contiguous 64 B line
// -> fully sector-efficient; ah (8 MB) + woh (2 MB) are L2/L3-hot. Each wave
// runs a private dependency-free K-loop (4 loads + 4 MFMA per BK=32 step) ->
// zero sync; 16 independent waves/CU self-hide all latency. This replaces the
// LDS-staged loop whose per-iter vmcnt(0)+2-barrier drain kept the kernel at
// ~170 TF despite a 3.4 us MFMA floor.
__global__ __launch_bounds__(256)
void gemm_out(const half_t* __restrict__ A, const half_t* __restrict__ W,
              float* __restrict__ outF)
{
    const int t    = threadIdx.x;
    const int lane = t & 63;
    const int wave = t >> 6;
    const int quad = lane >> 4;
    const int l16  = lane & 15;
    const int wr   = (wave >> 1) * 32;   // M offset within tile
    const int wc   = (wave & 1) * 32;    // N offset
    const int bm   = blockIdx.x, bn = blockIdx.y;

    const half_t* Ap0 = A + (size_t)(bm * 64 + wr      + l16) * HDIM + quad * 8;
    const half_t* Ap1 = A + (size_t)(bm * 64 + wr + 16 + l16) * HDIM + quad * 8;
    const half_t* Wp0 = W + (size_t)(bn * 64 + wc      + l16) * HDIM + quad * 8;
    const half_t* Wp1 = W + (size_t)(bn * 64 + wc + 16 + l16) * HDIM + quad * 8;

    float4v acc[2][2] = {};

#pragma unroll 4
    for (int kt = 0; kt < HDIM / 32; ++kt) {
        const int o = kt * 32;
        half8 a0 = *(const half8*)(Ap0 + o);
        half8 a1 = *(const half8*)(Ap1 + o);
        half8 b0 = *(const half8*)(Wp0 + o);
        half8 b1 = *(const half8*)(Wp1 + o);
        acc[0][0] = __builtin_amdgcn_mfma_f32_16x16x32_f16(a0, b0, acc[0][0], 0, 0, 0);
        acc[0][1] = __builtin_amdgcn_mfma_f32_16x16x32_f16(a0, b1, acc[0][1], 0, 0, 0);
        acc[1][0] = __builtin_amdgcn_mfma_f32_16x16x32_f16(a1, b0, acc[1][0], 0, 0, 0);
        acc[1][1] = __builtin_amdgcn_mfma_f32_16x16x32_f16(a1, b1, acc[1][1], 0, 0, 0);
    }

#pragma unroll
    for (int mb = 0; mb < 2; ++mb)
#pragma unroll
        for (int nb = 0; nb < 2; ++nb) {
            int row0 = bm * 64 + wr + mb * 16 + quad * 4;
            int col  = bn * 64 + wc + nb * 16 + l16;
#pragma unroll
            for (int r = 0; r < 4; ++r)
                outF[(size_t)(row0 + r) * HDIM + col] = acc[mb][nb][r];
        }
}

// ---------------- fused attention ----------------
// Reference semantics: softmax over ALL keys, THEN causal zeroing, NO renorm.
// v7 (best-measured 50.5 us, frozen): 128-key iterations, Ksh/Vsh double-
// buffered (64 KB, 2 blocks/CU = 16 waves/CU). Per iteration: stage K(T+1) +
// V(T+1) (issue-early/write-late), two independent 64-key half-chains
// {QK->exp->cvt->PV} between barriers.
__global__ __launch_bounds__(512, 4)
void attn_fused(const half_t* __restrict__ Qb, const half_t* __restrict__ Kb,
                const half_t* __restrict__ Vtb, half_t* __restrict__ AOut)
{
    const int bx = blockIdx.x;   // 0..15
    const int p  = bx >> 1;      // q-tile pair (p, 15-p), p in 0..7
    const int hf = bx & 1;       // which 64-row half of each tile
    const int bh = blockIdx.y;   // 0..31 (b*16+h)
    const int NT = SEQ / 128;    // 16 iterations of 128 keys

    __shared__ __align__(16) half_t Ksh[2][128][64];   // [buf][key][d], 32 KB
    __shared__ __align__(16) half_t Vsh[2][64][128];   // [buf][d][key], 32 KB

    const int t = threadIdx.x;
    const int wave = t >> 6, lane = t & 63, quad = lane >> 4, l16 = lane & 15;
    const int heavy = wave >> 2, wl = wave & 3;
    const int qtile = heavy ? (15 - p) : p;
    const int q0 = qtile * 128 + hf * 64 + wl * 16;   // wave's 16 q rows
    const int vtop = 15 - p;    // last V tile needed by this block (128-key units)

    // Q fragment (B-operand layout of 16x16x32)
    const half_t* Qp = Qb + ((size_t)bh * SEQ + q0 + l16) * DH + quad * 8;
    const half8 qf0 = *(const half8*)Qp;
    const half8 qf1 = *(const half8*)(Qp + 32);

    float4v o[4] = {};     // O^T accum
    float4v ls = {};       // 4 independent denominator chains

    // K DMA staging: wave stages rows wave*16 .. wave*16+15 (two 8-row chunks,
    // XOR chunk swizzle within each 8-row group)
    const int krow = lane >> 3, kpos = lane & 7;
    const int kchunk = kpos ^ krow;
    const half_t* Ksrc = Kb + ((size_t)bh * SEQ + wave * 16 + krow) * DH + kchunk * 8;
    const int ko1 = ((quad ^ (l16 & 7)) * 8);
    const int ko2 = ko1 ^ 32;

    // V staging: 512 threads x 2 uint4 = 64 x 128 tile; 16-chunk XOR swizzle
    const int sr  = t >> 3;          // d: 0..63
    const int sc0 = t & 7;           // chunks sc0 and sc0+8 (8 halfs each)
    const half_t* Vg = Vtb + ((size_t)bh * DH + sr) * SEQ + sc0 * 8;
    const int vso0 = ((sc0    ) ^ (sr & 15)) * 8;   // swizzled store offsets (halfs)
    const int vso1 = ((sc0 + 8) ^ (sr & 15)) * 8;

    // ---- prologue: stage K(0), V(0) ----
    {
        uint4 va0 = *(const uint4*)(Vg);
        uint4 va1 = *(const uint4*)(Vg + 64);
        glds16(Ksrc,          &Ksh[0][wave * 16][0]);
        glds16(Ksrc + 8 * DH, &Ksh[0][wave * 16 + 8][0]);
        *(uint4*)&Vsh[0][sr][vso0] = va0;
        *(uint4*)&Vsh[0][sr][vso1] = va1;
    }
    __asm__ volatile("s_waitcnt vmcnt(0)" ::: "memory");
    __asm__ volatile("s_waitcnt lgkmcnt(0)" ::: "memory");
    __builtin_amdgcn_s_barrier();
    __builtin_amdgcn_sched_barrier(0);

    for (int T = 0; T < NT; ++T) {
        const int cur = T & 1, nxt = cur ^ 1;
        const bool kn = (T + 1 < NT);
        const bool vn = kn && (T + 1 <= vtop);

        uint4 va0, va1;
        if (vn) {                         // issue-early
            va0 = *(const uint4*)(Vg + (T + 1) * 128);
            va1 = *(const uint4*)(Vg + (T + 1) * 128 + 64);
        }
        if (kn) {
            const half_t* Kn = Ksrc + (size_t)(T + 1) * 128 * DH;
            glds16(Kn,          &Ksh[nxt][wave * 16][0]);
            glds16(Kn + 8 * DH, &Ksh[nxt][wave * 16 + 8][0]);
        }

#pragma unroll
        for (int hh = 0; hh < 2; ++hh) {
            // S^T = K * Q^T over this 64-key half
            float4v sc[4];
            __builtin_amdgcn_s_setprio(1);
#pragma unroll
            for (int nb = 0; nb < 4; ++nb) {
                const half_t* kp = &Ksh[cur][hh * 64 + nb * 16 + l16][0];
                half8 kf0 = *(const half8*)(kp + ko1);
                half8 kf1 = *(const half8*)(kp + ko2);
                float4v a = {};
                a = __builtin_amdgcn_mfma_f32_16x16x32_f16(kf0, qf0, a, 0, 0, 0);
                a = __builtin_amdgcn_mfma_f32_16x16x32_f16(kf1, qf1, a, 0, 0, 0);
                sc[nb] = a;
            }
            __builtin_amdgcn_s_setprio(0);

            // P = exp2(sc); 4 independent partial-denominator chains
#pragma unroll
            for (int nb = 0; nb < 4; ++nb)
#pragma unroll
                for (int r = 0; r < 4; ++r) {
                    float e = __builtin_amdgcn_exp2f(sc[nb][r]);
                    sc[nb][r] = e;
                    ls[r] += e;
                }

            const int kbase = T * 128 + hh * 64;
            if (kbase <= q0 + 15) {   // wave-uniform: at least one unmasked key
                if (kbase + 63 > q0) {   // straddle: post-softmax zeroing
                    int qg = q0 + l16;
#pragma unroll
                    for (int nb = 0; nb < 4; ++nb)
#pragma unroll
                        for (int r = 0; r < 4; ++r)
                            if (kbase + nb * 16 + quad * 4 + r > qg) sc[nb][r] = 0.f;
                }
                half4 pf[4];
#pragma unroll
                for (int nb = 0; nb < 4; ++nb) {
                    union { fp16x2 v2[2]; half4 v4; } u;
                    u.v2[0] = __builtin_amdgcn_cvt_pkrtz(sc[nb][0], sc[nb][1]);
                    u.v2[1] = __builtin_amdgcn_cvt_pkrtz(sc[nb][2], sc[nb][3]);
                    pf[nb] = u.v4;
                }
                __builtin_amdgcn_s_setprio(1);
#pragma unroll
                for (int md = 0; md < 4; ++md) {
                    const char* vrow = (const char*)&Vsh[cur][md * 16 + l16][0];
#pragma unroll
                    for (int nb = 0; nb < 4; ++nb) {
                        const int chunk = (hh * 8 + nb * 2 + (quad >> 1)) ^ l16;
                        half4 vf = *(const half4*)(vrow + chunk * 16 + (quad & 1) * 8);
                        o[md] = __builtin_amdgcn_mfma_f32_16x16x16f16(vf, pf[nb], o[md], 0, 0, 0);
                    }
                }
                __builtin_amdgcn_s_setprio(0);
            }
        }

        if (vn) {                         // write-late into the other buffer
            *(uint4*)&Vsh[nxt][sr][vso0] = va0;
            *(uint4*)&Vsh[nxt][sr][vso1] = va1;
        }
        __asm__ volatile("s_waitcnt vmcnt(0)" ::: "memory");
        __asm__ volatile("s_waitcnt lgkmcnt(0)" ::: "memory");
        __builtin_amdgcn_s_barrier();
        __builtin_amdgcn_sched_barrier(0);
    }

    // epilogue: denominator (2 shuffles) + O^T transpose via per-wave LDS scratch.
    const int b = bh >> 4, h = bh & 15;
    const int orow = lane >> 2, occ = (lane & 3) * 16;
    half_t* scr = (heavy ? (half_t*)Vsh : (half_t*)Ksh) + wl * 1152;
    half_t (*Osh)[72] = (half_t(*)[72])scr;   // 16 x 72
    {
        float rs = (ls[0] + ls[1]) + (ls[2] + ls[3]);
        rs += __shfl_xor(rs, 16, 64);
        rs += __shfl_xor(rs, 32, 64);
        const float inv = 1.0f / rs;
#pragma unroll
        for (int md = 0; md < 4; ++md)
#pragma unroll
            for (int r = 0; r < 4; ++r)
                Osh[l16][md * 16 + quad * 4 + r] = (half_t)(o[md][r] * inv);
        __asm__ volatile("s_waitcnt lgkmcnt(0)" ::: "memory");
        uint4 o0 = *(const uint4*)&Osh[orow][occ];
        uint4 o1 = *(const uint4*)&Osh[orow][occ + 8];
        const int s = q0 + orow;
        half_t* dst = AOut + ((size_t)(b * SEQ + s)) * HDIM + h * DH + occ;
        *(uint4*)dst       = o0;
        *(uint4*)(dst + 8) = o1;
    }
}

// ---------------- launch ----------------
extern "C" void kernel_launch(void* const* d_in, const int* in_sizes, int n_in,
                              void* d_out, int out_size, void* d_ws, size_t ws_size,
                              hipStream_t stream)
{
    const float* x  = (const float*)d_in[0];
    const float* wq = (const float*)d_in[1];
    const float* wk = (const float*)d_in[2];
    const float* wv = (const float*)d_in[3];
    const float* wo = (const float*)d_in[4];
    float* out = (float*)d_out;

    char* ws = (char*)d_ws;
    size_t off = 0;
    auto alloc = [&](size_t bytes) -> void* {
        void* p = ws + off;
        off += (bytes + 255) & ~(size_t)255;
        return p;
    };
    half_t* xh   = (half_t*)alloc((size_t)MTOT * HDIM * 2);   // 8 MB
    half_t* wqh  = (half_t*)alloc((size_t)HDIM * HDIM * 2);   // 2 MB
    half_t* wkh  = (half_t*)alloc((size_t)HDIM * HDIM * 2);
    half_t* wvh  = (half_t*)alloc((size_t)HDIM * HDIM * 2);
    half_t* woh  = (half_t*)alloc((size_t)HDIM * HDIM * 2);
    half_t* Qb   = (half_t*)alloc((size_t)BHTOT * SEQ * DH * 2);  // 8 MB
    half_t* Kb   = (half_t*)alloc((size_t)BHTOT * SEQ * DH * 2);
    half_t* Vtb  = (half_t*)alloc((size_t)BHTOT * SEQ * DH * 2);
    half_t* ah   = (half_t*)alloc((size_t)MTOT * HDIM * 2);       // 8 MB
    float2* rope = (float2*)alloc((size_t)SEQ * 32 * sizeof(float2));

    prep<<<4352, 256, 0, stream>>>(x, wq, wk, wv, wo, xh, wqh, wkh, wvh, woh, rope);

    // Q, K, V in one launch (grid.z selects weight + epilogue)
    gemm_qkv<<<dim3(32, 8, 3), 256, 0, stream>>>(xh, wqh, wkh, wvh,
                                                 Qb, Kb, Vtb, rope);
    // attn: 512-thread blocks, 512 blocks = 2 blocks/CU, 128-key iterations
    attn_fused<<<dim3(16, 32), 512, 0, stream>>>(Qb, Kb, Vtb, ah);
    // out = attn @ w_o^T: 64x64 tiles, no-LDS no-barrier direct-fragment loads
    gemm_out<<<dim3(64, 16), 256, 0, stream>>>(ah, woh, out);
}

// Round 13
// 178.805 us; speedup vs baseline: 1.2331x; 1.2331x over previous
//
#include <hip/hip_runtime.h>
#include <math.h>

#define SEQ   2048
#define HDIM  1024
#define NH    16
#define DH    64
#define MTOT  4096   // B*S
#define BHTOT 32     // B*NH

typedef _Float16 half_t;
typedef __attribute__((ext_vector_type(2))) __fp16 fp16x2;
typedef __attribute__((ext_vector_type(4))) _Float16 half4;
typedef __attribute__((ext_vector_type(8))) _Float16 half8;
typedef __attribute__((ext_vector_type(4))) float float4v;

// async global->LDS DMA, 16 B per lane; LDS dest = wave-uniform base + lane*16
typedef __attribute__((address_space(1))) const unsigned int guint;
typedef __attribute__((address_space(3))) unsigned int luint;
__device__ __forceinline__ void glds16(const half_t* g, half_t* l) {
    __builtin_amdgcn_global_load_lds((guint*)g, (luint*)l, 16, 0, 0);
}

// ---------------- fused prologue: 5 fp32->fp16 casts + rope table ----------------
// 8 floats/thread (two float4 loads -> one uint4 store). Grid 4352.
__global__ __launch_bounds__(256)
void prep(const float* __restrict__ x,  const float* __restrict__ wq,
          const float* __restrict__ wk, const float* __restrict__ wv,
          const float* __restrict__ wo,
          half_t* __restrict__ xh,  half_t* __restrict__ wqh,
          half_t* __restrict__ wkh, half_t* __restrict__ wvh,
          half_t* __restrict__ woh, float2* __restrict__ rope)
{
    const int bid = blockIdx.x;
    if (bid < 4096) {
        int i = bid * 256 + threadIdx.x;   // 0..1048575, 8 floats each
        const float4* s; uint4* d; int j;
        if (i < 524288) { s = (const float4*)x; d = (uint4*)xh; j = i; }
        else {
            int k = i - 524288;
            int w = k >> 17; j = k & 131071;
            s = (const float4*)((w == 0) ? wq : (w == 1) ? wk : (w == 2) ? wv : wo);
            d = (uint4*)((w == 0) ? wqh : (w == 1) ? wkh : (w == 2) ? wvh : woh);
        }
        float4 v0 = s[2 * j], v1 = s[2 * j + 1];
        union { half_t h[8]; uint4 u; } tmp;
        tmp.h[0] = (half_t)v0.x; tmp.h[1] = (half_t)v0.y;
        tmp.h[2] = (half_t)v0.z; tmp.h[3] = (half_t)v0.w;
        tmp.h[4] = (half_t)v1.x; tmp.h[5] = (half_t)v1.y;
        tmp.h[6] = (half_t)v1.z; tmp.h[7] = (half_t)v1.w;
        d[j] = tmp.u;
    } else {
        int tt = (bid - 4096) * 256 + threadIdx.x;   // 0 .. SEQ*32-1
        int s = tt >> 5, j = tt & 31;
        float inv = powf(10000.0f, -(float)j / 32.0f);
        float ang = (float)s * inv;
        rope[tt] = make_float2(cosf(ang), sinf(ang));
    }
}

// ---------------- GEMM: QKV only. C = A(4096x1024,f16) * W^T, 128x128 tiles ----
// v6: BK=32 + 3-BUFFER RING with counted vmcnt (T4): stage(t+2) issued at
// iter t, end-of-iter s_waitcnt vmcnt(4) leaves t+2's 4 DMAs in flight --
// the queue never drains to zero in steady state (r9's dbuf still paid a
// vmcnt(0) drain each iter: ~200 cy exposed x 32 iters). Ledger: prologue
// stages 0,1 then vmcnt(4) [0 landed, 1 flying]; iter kt stages kt+2 (8
// outstanding), end vmcnt(4) [kt+1 landed]; tails kt=NT-2 -> vmcnt(0),
// kt=NT-1 trivial. Recycled buffer (kt+2)%3 is safe: its DMA is issued
// after the barrier that ends its last reader (iter kt-1). LDS 48 KB ->
// 3 blocks/CU (m97's proven residency, not the m132 2-block cliff).
__global__ __launch_bounds__(256, 4)
void gemm_qkv(const half_t* __restrict__ A,
              const half_t* __restrict__ w0, const half_t* __restrict__ w1,
              const half_t* __restrict__ w2,
              half_t* __restrict__ Qb, half_t* __restrict__ Kb,
              half_t* __restrict__ Vtb,
              const float2* __restrict__ rope)
{
    const int mode = blockIdx.z;
    const half_t* Bw = (mode == 1) ? w1 : (mode == 2) ? w2 : w0;

    __shared__ __align__(16) half_t Tsh[3][2][128][32];   // [ring][A|B][row][32], 48 KB

    const int t    = threadIdx.x;
    const int lane = t & 63;
    const int wave = t >> 6;
    const int quad = lane >> 4;
    const int l16  = lane & 15;
    const int wr   = (wave >> 1) * 64;
    const int wc   = (wave & 1) * 64;
    const int bm   = blockIdx.x, bn = blockIdx.y;

    // staging: one glds16 covers 16 rows x 64 B; chunk XOR-swizzled by row&3
    const int srow   = lane >> 2;               // 0..15 within a 16-row DMA chunk
    const int schunk = (lane & 3) ^ (srow & 3); // line-local pre-swizzle (16B chunks)
    const half_t* Asrc = A  + (size_t)(bm * 128 + srow) * HDIM + schunk * 8;
    const half_t* Bsrc = Bw + (size_t)(bn * 128 + srow) * HDIM + schunk * 8;
    const int swz = (l16 & 3) << 4;             // read-side XOR (byte offset)

    auto stage = [&](int kt, int buf) {
        const half_t* Ak = Asrc + kt * 32;
        const half_t* Bk = Bsrc + kt * 32;
        glds16(Ak + (size_t)(wave * 32)      * HDIM, &Tsh[buf][0][wave * 32][0]);
        glds16(Ak + (size_t)(wave * 32 + 16) * HDIM, &Tsh[buf][0][wave * 32 + 16][0]);
        glds16(Bk + (size_t)(wave * 32)      * HDIM, &Tsh[buf][1][wave * 32][0]);
        glds16(Bk + (size_t)(wave * 32 + 16) * HDIM, &Tsh[buf][1][wave * 32 + 16][0]);
    };

    float4v acc[4][4] = {};
    const int NT = HDIM / 32;

    stage(0, 0);
    stage(1, 1);
    __asm__ volatile("s_waitcnt vmcnt(4)" ::: "memory");   // tile0 landed, tile1 flying
    __builtin_amdgcn_s_barrier();
    __builtin_amdgcn_sched_barrier(0);

    int i0 = 0, i1 = 1, i2 = 2;   // ring: compute, next, stage-target
    for (int kt = 0; kt < NT; ++kt) {
        const bool s2 = (kt + 2 < NT);
        if (s2) stage(kt + 2, i2);            // prefetch 2 ahead
        const int cb = (quad << 4) ^ swz;
        half8 af[4], bf[4];
#pragma unroll
        for (int mb = 0; mb < 4; ++mb)
            af[mb] = *(const half8*)((const char*)&Tsh[i0][0][wr + mb * 16 + l16][0] + cb);
#pragma unroll
        for (int nb = 0; nb < 4; ++nb)
            bf[nb] = *(const half8*)((const char*)&Tsh[i0][1][wc + nb * 16 + l16][0] + cb);
#pragma unroll
        for (int mb = 0; mb < 4; ++mb)
#pragma unroll
            for (int nb = 0; nb < 4; ++nb)
                acc[mb][nb] = __builtin_amdgcn_mfma_f32_16x16x32_f16(af[mb], bf[nb], acc[mb][nb], 0, 0, 0);
        if (s2) { __asm__ volatile("s_waitcnt vmcnt(4)" ::: "memory"); }   // t+1 landed
        else    { __asm__ volatile("s_waitcnt vmcnt(0)" ::: "memory"); }
        __builtin_amdgcn_s_barrier();
        __builtin_amdgcn_sched_barrier(0);
        const int tmp = i0; i0 = i1; i1 = i2; i2 = tmp;
    }

    if (mode == 2) {  // V, transposed store: Vtb[bh][d][s]
#pragma unroll
        for (int mb = 0; mb < 4; ++mb)
#pragma unroll
            for (int nb = 0; nb < 4; ++nb) {
                int row0 = bm * 128 + wr + mb * 16 + quad * 4;
                int col  = bn * 128 + wc + nb * 16 + l16;
                int b = row0 >> 11, s0 = row0 & 2047;
                int h = col >> 6,  dd = col & 63;
                union { half_t h4[4]; uint2 u; } tmp;
#pragma unroll
                for (int r = 0; r < 4; ++r) tmp.h4[r] = (half_t)acc[mb][nb][r];
                *(uint2*)&Vtb[((size_t)((b * NH + h) * DH + dd)) * SEQ + s0] = tmp.u;
            }
        return;
    }
    // mode 0 (Q: rope + scale) / mode 1 (K: rope)
    {
        half_t* Ob = (mode == 0) ? Qb : Kb;
        const float scl = (mode == 0) ? 0.125f * 1.44269504088896f : 1.0f;
        const int h = (bn * 128 + wc) >> 6;   // wave's 64 cols = one head
        // per-wave fp32 bounce [16][68], overlaid on the 48 KB tile LDS
        float* E = (float*)&Tsh[0][0][0][0] + wave * 1088;
#pragma unroll
        for (int mb = 0; mb < 4; ++mb) {
#pragma unroll
            for (int nb = 0; nb < 4; ++nb)
#pragma unroll
                for (int r = 0; r < 4; ++r)
                    E[(quad * 4 + r) * 68 + nb * 16 + l16] = acc[mb][nb][r];
            __asm__ volatile("s_waitcnt lgkmcnt(0)" ::: "memory");  // wave-private region
#pragma unroll
            for (int c = 0; c < 2; ++c) {
                const int uidx = c * 64 + lane;
                const int row = uidx >> 3, ch = uidx & 7;
                const int sg = bm * 128 + wr + mb * 16 + row;
                const int b = sg >> 11, s = sg & 2047;
                const float* Er = E + row * 68 + ch * 8;
                const float4 e0 = *(const float4*)Er;
                const float4 e1 = *(const float4*)(Er + 4);
                const float4* rp = (const float4*)(rope + (size_t)s * 32 + ch * 4);
                const float4 r01 = rp[0];   // cos0,sin0,cos1,sin1
                const float4 r23 = rp[1];
                union { half_t hh[8]; uint4 u; } o;
                o.hh[0] = (half_t)((e0.x * r01.x - e0.y * r01.y) * scl);
                o.hh[1] = (half_t)((e0.x * r01.y + e0.y * r01.x) * scl);
                o.hh[2] = (half_t)((e0.z * r01.z - e0.w * r01.w) * scl);
                o.hh[3] = (half_t)((e0.z * r01.w + e0.w * r01.z) * scl);
                o.hh[4] = (half_t)((e1.x * r23.x - e1.y * r23.y) * scl);
                o.hh[5] = (half_t)((e1.x * r23.y + e1.y * r23.x) * scl);
                o.hh[6] = (half_t)((e1.z * r23.z - e1.w * r23.w) * scl);
                o.hh[7] = (half_t)((e1.z * r23.w + e1.w * r23.z) * scl);
                *(uint4*)&Ob[((size_t)((b * NH + h) * SEQ + s)) * DH + ch * 8] = o.u;
            }
            // per-wave DS ops are in-order: reads above complete before next mb's writes
        }
    }
}

// ---------------- output GEMM: out(f32) = ah(4096x1024,f16) @ wo^T ----------------
// REVERTED to r11's LDS version (measured ~23 us via r12's A/B): 64x64 tiles,
// grid (64,16) = 1024 blocks = 4 blocks/CU, 2-phase prefetch. r12's no-LDS
// variant was 62.8 us -- L2-latency-bound (MfmaUtil 4.9%), direct-fragment
// loads lack the MLP to cover ~400 cy L2 latency. Lesson recorded.
__global__ __launch_bounds__(256, 4)
void gemm_out(const half_t* __restrict__ A, const half_t* __restrict__ W,
              float* __restrict__ outF)
{
    __shared__ __align__(16) half_t Ash[2][64][64];    // 16 KB
    __shared__ __align__(16) half_t Bsh[2][64][64];    // 16 KB

    const int t    = threadIdx.x;
    const int lane = t & 63;
    const int wave = t >> 6;
    const int quad = lane >> 4;
    const int l16  = lane & 15;
    const int wr   = (wave >> 1) * 32;   // M offset within tile
    const int wc   = (wave & 1) * 32;    // N offset
    const int bm   = blockIdx.x, bn = blockIdx.y;

    const int srow   = lane >> 3;
    const int schunk = (lane & 7) ^ (srow & 3);
    const half_t* Asrc = A + (size_t)(bm * 64 + srow) * HDIM + schunk * 8;
    const half_t* Bsrc = W + (size_t)(bn * 64 + srow) * HDIM + schunk * 8;
    const int swz = (l16 & 3) << 4;

    auto stage = [&](int kt, int buf) {
        const half_t* Ak = Asrc + kt * 64;
        const half_t* Bk = Bsrc + kt * 64;
#pragma unroll
        for (int c = 0; c < 2; ++c) {
            const int r8 = wave * 16 + c * 8;
            glds16(Ak + (size_t)r8 * HDIM, &Ash[buf][r8][0]);
            glds16(Bk + (size_t)r8 * HDIM, &Bsh[buf][r8][0]);
        }
    };

    float4v acc[2][2] = {};

    stage(0, 0);
    __asm__ volatile("s_waitcnt vmcnt(0)" ::: "memory");
    __builtin_amdgcn_s_barrier();
    __builtin_amdgcn_sched_barrier(0);

    for (int kt = 0; kt < HDIM / 64; ++kt) {
        const int cur = kt & 1, nxt = cur ^ 1;
        if (kt + 1 < HDIM / 64) stage(kt + 1, nxt);   // prefetch under compute
#pragma unroll
        for (int kk = 0; kk < 2; ++kk) {
            const int cb = ((quad << 4) | (kk << 6)) ^ swz;
            half8 af[2], bf[2];
#pragma unroll
            for (int mb = 0; mb < 2; ++mb)
                af[mb] = *(const half8*)((const char*)&Ash[cur][wr + mb * 16 + l16][0] + cb);
#pragma unroll
            for (int nb = 0; nb < 2; ++nb)
                bf[nb] = *(const half8*)((const char*)&Bsh[cur][wc + nb * 16 + l16][0] + cb);
#pragma unroll
            for (int mb = 0; mb < 2; ++mb)
#pragma unroll
                for (int nb = 0; nb < 2; ++nb)
                    acc[mb][nb] = __builtin_amdgcn_mfma_f32_16x16x32_f16(af[mb], bf[nb], acc[mb][nb], 0, 0, 0);
        }
        __asm__ volatile("s_waitcnt vmcnt(0)" ::: "memory");  // next tile landed
        __builtin_amdgcn_s_barrier();
        __builtin_amdgcn_sched_barrier(0);
    }

#pragma unroll
    for (int mb = 0; mb < 2; ++mb)
#pragma unroll
        for (int nb = 0; nb < 2; ++nb) {
            int row0 = bm * 64 + wr + mb * 16 + quad * 4;
            int col  = bn * 64 + wc + nb * 16 + l16;
#pragma unroll
            for (int r = 0; r < 4; ++r)
                outF[(size_t)(row0 + r) * HDIM + col] = acc[mb][nb][r];
        }
}

// ---------------- fused attention ----------------
// Reference semantics: softmax over ALL keys, THEN causal zeroing, NO renorm.
// v7 (best-measured 50.5 us, frozen): 128-key iterations, Ksh/Vsh double-
// buffered (64 KB, 2 blocks/CU = 16 waves/CU). Per iteration: stage K(T+1) +
// V(T+1) (issue-early/write-late), two independent 64-key half-chains
// {QK->exp->cvt->PV} between barriers.
__global__ __launch_bounds__(512, 4)
void attn_fused(const half_t* __restrict__ Qb, const half_t* __restrict__ Kb,
                const half_t* __restrict__ Vtb, half_t* __restrict__ AOut)
{
    const int bx = blockIdx.x;   // 0..15
    const int p  = bx >> 1;      // q-tile pair (p, 15-p), p in 0..7
    const int hf = bx & 1;       // which 64-row half of each tile
    const int bh = blockIdx.y;   // 0..31 (b*16+h)
    const int NT = SEQ / 128;    // 16 iterations of 128 keys

    __shared__ __align__(16) half_t Ksh[2][128][64];   // [buf][key][d], 32 KB
    __shared__ __align__(16) half_t Vsh[2][64][128];   // [buf][d][key], 32 KB

    const int t = threadIdx.x;
    const int wave = t >> 6, lane = t & 63, quad = lane >> 4, l16 = lane & 15;
    const int heavy = wave >> 2, wl = wave & 3;
    const int qtile = heavy ? (15 - p) : p;
    const int q0 = qtile * 128 + hf * 64 + wl * 16;   // wave's 16 q rows
    const int vtop = 15 - p;    // last V tile needed by this block (128-key units)

    // Q fragment (B-operand layout of 16x16x32)
    const half_t* Qp = Qb + ((size_t)bh * SEQ + q0 + l16) * DH + quad * 8;
    const half8 qf0 = *(const half8*)Qp;
    const half8 qf1 = *(const half8*)(Qp + 32);

    float4v o[4] = {};     // O^T accum
    float4v ls = {};       // 4 independent denominator chains

    // K DMA staging: wave stages rows wave*16 .. wave*16+15 (two 8-row chunks,
    // XOR chunk swizzle within each 8-row group)
    const int krow = lane >> 3, kpos = lane & 7;
    const int kchunk = kpos ^ krow;
    const half_t* Ksrc = Kb + ((size_t)bh * SEQ + wave * 16 + krow) * DH + kchunk * 8;
    const int ko1 = ((quad ^ (l16 & 7)) * 8);
    const int ko2 = ko1 ^ 32;

    // V staging: 512 threads x 2 uint4 = 64 x 128 tile; 16-chunk XOR swizzle
    const int sr  = t >> 3;          // d: 0..63
    const int sc0 = t & 7;           // chunks sc0 and sc0+8 (8 halfs each)
    const half_t* Vg = Vtb + ((size_t)bh * DH + sr) * SEQ + sc0 * 8;
    const int vso0 = ((sc0    ) ^ (sr & 15)) * 8;   // swizzled store offsets (halfs)
    const int vso1 = ((sc0 + 8) ^ (sr & 15)) * 8;

    // ---- prologue: stage K(0), V(0) ----
    {
        uint4 va0 = *(const uint4*)(Vg);
        uint4 va1 = *(const uint4*)(Vg + 64);
        glds16(Ksrc,          &Ksh[0][wave * 16][0]);
        glds16(Ksrc + 8 * DH, &Ksh[0][wave * 16 + 8][0]);
        *(uint4*)&Vsh[0][sr][vso0] = va0;
        *(uint4*)&Vsh[0][sr][vso1] = va1;
    }
    __asm__ volatile("s_waitcnt vmcnt(0)" ::: "memory");
    __asm__ volatile("s_waitcnt lgkmcnt(0)" ::: "memory");
    __builtin_amdgcn_s_barrier();
    __builtin_amdgcn_sched_barrier(0);

    for (int T = 0; T < NT; ++T) {
        const int cur = T & 1, nxt = cur ^ 1;
        const bool kn = (T + 1 < NT);
        const bool vn = kn && (T + 1 <= vtop);

        uint4 va0, va1;
        if (vn) {                         // issue-early
            va0 = *(const uint4*)(Vg + (T + 1) * 128);
            va1 = *(const uint4*)(Vg + (T + 1) * 128 + 64);
        }
        if (kn) {
            const half_t* Kn = Ksrc + (size_t)(T + 1) * 128 * DH;
            glds16(Kn,          &Ksh[nxt][wave * 16][0]);
            glds16(Kn + 8 * DH, &Ksh[nxt][wave * 16 + 8][0]);
        }

#pragma unroll
        for (int hh = 0; hh < 2; ++hh) {
            // S^T = K * Q^T over this 64-key half
            float4v sc[4];
            __builtin_amdgcn_s_setprio(1);
#pragma unroll
            for (int nb = 0; nb < 4; ++nb) {
                const half_t* kp = &Ksh[cur][hh * 64 + nb * 16 + l16][0];
                half8 kf0 = *(const half8*)(kp + ko1);
                half8 kf1 = *(const half8*)(kp + ko2);
                float4v a = {};
                a = __builtin_amdgcn_mfma_f32_16x16x32_f16(kf0, qf0, a, 0, 0, 0);
                a = __builtin_amdgcn_mfma_f32_16x16x32_f16(kf1, qf1, a, 0, 0, 0);
                sc[nb] = a;
            }
            __builtin_amdgcn_s_setprio(0);

            // P = exp2(sc); 4 independent partial-denominator chains
#pragma unroll
            for (int nb = 0; nb < 4; ++nb)
#pragma unroll
                for (int r = 0; r < 4; ++r) {
                    float e = __builtin_amdgcn_exp2f(sc[nb][r]);
                    sc[nb][r] = e;
                    ls[r] += e;
                }

            const int kbase = T * 128 + hh * 64;
            if (kbase <= q0 + 15) {   // wave-uniform: at least one unmasked key
                if (kbase + 63 > q0) {   // straddle: post-softmax zeroing
                    int qg = q0 + l16;
#pragma unroll
                    for (int nb = 0; nb < 4; ++nb)
#pragma unroll
                        for (int r = 0; r < 4; ++r)
                            if (kbase + nb * 16 + quad * 4 + r > qg) sc[nb][r] = 0.f;
                }
                half4 pf[4];
#pragma unroll
                for (int nb = 0; nb < 4; ++nb) {
                    union { fp16x2 v2[2]; half4 v4; } u;
                    u.v2[0] = __builtin_amdgcn_cvt_pkrtz(sc[nb][0], sc[nb][1]);
                    u.v2[1] = __builtin_amdgcn_cvt_pkrtz(sc[nb][2], sc[nb][3]);
                    pf[nb] = u.v4;
                }
                __builtin_amdgcn_s_setprio(1);
#pragma unroll
                for (int md = 0; md < 4; ++md) {
                    const char* vrow = (const char*)&Vsh[cur][md * 16 + l16][0];
#pragma unroll
                    for (int nb = 0; nb < 4; ++nb) {
                        const int chunk = (hh * 8 + nb * 2 + (quad >> 1)) ^ l16;
                        half4 vf = *(const half4*)(vrow + chunk * 16 + (quad & 1) * 8);
                        o[md] = __builtin_amdgcn_mfma_f32_16x16x16f16(vf, pf[nb], o[md], 0, 0, 0);
                    }
                }
                __builtin_amdgcn_s_setprio(0);
            }
        }

        if (vn) {                         // write-late into the other buffer
            *(uint4*)&Vsh[nxt][sr][vso0] = va0;
            *(uint4*)&Vsh[nxt][sr][vso1] = va1;
        }
        __asm__ volatile("s_waitcnt vmcnt(0)" ::: "memory");
        __asm__ volatile("s_waitcnt lgkmcnt(0)" ::: "memory");
        __builtin_amdgcn_s_barrier();
        __builtin_amdgcn_sched_barrier(0);
    }

    // epilogue: denominator (2 shuffles) + O^T transpose via per-wave LDS scratch.
    const int b = bh >> 4, h = bh & 15;
    const int orow = lane >> 2, occ = (lane & 3) * 16;
    half_t* scr = (heavy ? (half_t*)Vsh : (half_t*)Ksh) + wl * 1152;
    half_t (*Osh)[72] = (half_t(*)[72])scr;   // 16 x 72
    {
        float rs = (ls[0] + ls[1]) + (ls[2] + ls[3]);
        rs += __shfl_xor(rs, 16, 64);
        rs += __shfl_xor(rs, 32, 64);
        const float inv = 1.0f / rs;
#pragma unroll
        for (int md = 0; md < 4; ++md)
#pragma unroll
            for (int r = 0; r < 4; ++r)
                Osh[l16][md * 16 + quad * 4 + r] = (half_t)(o[md][r] * inv);
        __asm__ volatile("s_waitcnt lgkmcnt(0)" ::: "memory");
        uint4 o0 = *(const uint4*)&Osh[orow][occ];
        uint4 o1 = *(const uint4*)&Osh[orow][occ + 8];
        const int s = q0 + orow;
        half_t* dst = AOut + ((size_t)(b * SEQ + s)) * HDIM + h * DH + occ;
        *(uint4*)dst       = o0;
        *(uint4*)(dst + 8) = o1;
    }
}

// ---------------- launch ----------------
extern "C" void kernel_launch(void* const* d_in, const int* in_sizes, int n_in,
                              void* d_out, int out_size, void* d_ws, size_t ws_size,
                              hipStream_t stream)
{
    const float* x  = (const float*)d_in[0];
    const float* wq = (const float*)d_in[1];
    const float* wk = (const float*)d_in[2];
    const float* wv = (const float*)d_in[3];
    const float* wo = (const float*)d_in[4];
    float* out = (float*)d_out;

    char* ws = (char*)d_ws;
    size_t off = 0;
    auto alloc = [&](size_t bytes) -> void* {
        void* p = ws + off;
        off += (bytes + 255) & ~(size_t)255;
        return p;
    };
    half_t* xh   = (half_t*)alloc((size_t)MTOT * HDIM * 2);   // 8 MB
    half_t* wqh  = (half_t*)alloc((size_t)HDIM * HDIM * 2);   // 2 MB
    half_t* wkh  = (half_t*)alloc((size_t)HDIM * HDIM * 2);
    half_t* wvh  = (half_t*)alloc((size_t)HDIM * HDIM * 2);
    half_t* woh  = (half_t*)alloc((size_t)HDIM * HDIM * 2);
    half_t* Qb   = (half_t*)alloc((size_t)BHTOT * SEQ * DH * 2);  // 8 MB
    half_t* Kb   = (half_t*)alloc((size_t)BHTOT * SEQ * DH * 2);
    half_t* Vtb  = (half_t*)alloc((size_t)BHTOT * SEQ * DH * 2);
    half_t* ah   = (half_t*)alloc((size_t)MTOT * HDIM * 2);       // 8 MB
    float2* rope = (float2*)alloc((size_t)SEQ * 32 * sizeof(float2));

    prep<<<4352, 256, 0, stream>>>(x, wq, wk, wv, wo, xh, wqh, wkh, wvh, woh, rope);

    // Q, K, V in one launch (grid.z selects weight + epilogue)
    gemm_qkv<<<dim3(32, 8, 3), 256, 0, stream>>>(xh, wqh, wkh, wvh,
                                                 Qb, Kb, Vtb, rope);
    // attn: 512-thread blocks, 512 blocks = 2 blocks/CU, 128-key iterations
    attn_fused<<<dim3(16, 32), 512, 0, stream>>>(Qb, Kb, Vtb, ah);
    // out = attn @ w_o^T: 64x64 tiles, 1024 blocks = 4 blocks/CU, 2-phase
    gemm_out<<<dim3(64, 16), 256, 0, stream>>>(ah, woh, out);
}